// Round 7
// baseline (291.061 us; speedup 1.0000x reference)
//
#include <hip/hip_runtime.h>
#include <math.h>

#define SS 2048
#define EE 1024

using bf16x8 = __attribute__((ext_vector_type(8))) short;
using f32x4  = __attribute__((ext_vector_type(4))) float;

// round-half-up, 2 VALU
__device__ inline short f2bf_r(float x) {
    return (short)((__builtin_bit_cast(unsigned, x) + 0x8000u) >> 16);
}
// pack 2 floats -> 2 bf16 in one dword: 2 adds + 1 v_perm
__device__ inline unsigned pk_bf16(float a, float b) {
    unsigned ua = __builtin_bit_cast(unsigned, a) + 0x8000u;
    unsigned ub = __builtin_bit_cast(unsigned, b) + 0x8000u;
    return __builtin_amdgcn_perm(ub, ua, 0x07060302u);
}

// ---------- weight prep: LDS-tiled coalesced transposes + rope table ----------
// grid: 240 blocks. 0-191: Wall tiles (64 per source); 192-207: Wo4; 208-239: RT.
__global__ __launch_bounds__(256) void prep_kernel(const float* __restrict__ Wq,
                                                   const float* __restrict__ Wk,
                                                   const float* __restrict__ Wv,
                                                   const float* __restrict__ Wo,
                                                   short* __restrict__ Wall,
                                                   short* __restrict__ Wo4,
                                                   float2* __restrict__ RT) {
    __shared__ float T[64][65];
    int bid = blockIdx.x, tid = threadIdx.x;
    if (bid < 192) {
        int src = bid >> 6;            // 0=Wq(sum+scale) 1=Wk 2=Wv
        int j = bid & 63;
        int et = j & 15, ct = j >> 4;  // e-tile(64) x c-tile(64)
        int e0 = et * 64, c0 = ct * 64;
        #pragma unroll
        for (int p = 0; p < 4; p++) {
            int el = p * 16 + (tid >> 4);
            int c4 = (tid & 15) * 4;
            float4 v;
            if (src == 0) {
                float4 s = {0, 0, 0, 0};
                #pragma unroll
                for (int g = 0; g < 4; g++) {
                    float4 w = *(const float4*)&Wq[(size_t)(e0 + el) * 1024 + ct * 256 + g * 64 + c4];
                    s.x += w.x; s.y += w.y; s.z += w.z; s.w += w.w;
                }
                v.x = s.x * 0.18033688011112042f; v.y = s.y * 0.18033688011112042f;
                v.z = s.z * 0.18033688011112042f; v.w = s.w * 0.18033688011112042f;
            } else if (src == 1) {
                v = *(const float4*)&Wk[(size_t)(e0 + el) * 256 + c0 + c4];
            } else {
                v = *(const float4*)&Wv[(size_t)(e0 + el) * 256 + c0 + c4];
            }
            T[c4][el] = v.x; T[c4 + 1][el] = v.y; T[c4 + 2][el] = v.z; T[c4 + 3][el] = v.w;
        }
        __syncthreads();
        #pragma unroll
        for (int p = 0; p < 8; p++) {
            int c = p * 8 + (tid >> 5);
            int e2 = (tid & 31) * 2;
            unsigned u = pk_bf16(T[c][e2], T[c][e2 + 1]);
            *(unsigned*)&Wall[(size_t)(src * 256 + c0 + c) * 1024 + e0 + e2] = u;
        }
    } else if (bid < 208) {
        int e0 = (bid - 192) * 64;
        #pragma unroll
        for (int p = 0; p < 4; p++) {
            int d = p * 16 + (tid >> 4);
            int e4 = (tid & 15) * 4;
            float4 v = *(const float4*)&Wo[(size_t)d * 1024 + e0 + e4];
            T[e4][d] = v.x; T[e4 + 1][d] = v.y; T[e4 + 2][d] = v.z; T[e4 + 3][d] = v.w;
        }
        __syncthreads();
        #pragma unroll
        for (int p = 0; p < 8; p++) {
            int e = p * 8 + (tid >> 5);
            int d2 = (tid & 31) * 2;
            unsigned u = pk_bf16(0.25f * T[e][d2], 0.25f * T[e][d2 + 1]);
            #pragma unroll
            for (int h = 0; h < 4; h++)
                *(unsigned*)&Wo4[(size_t)(e0 + e) * 256 + h * 64 + d2] = u;
        }
    } else {
        int gi = (bid - 208) * 256 + tid;
        #pragma unroll
        for (int u = 0; u < 8; u++) {
            int idx = u * 8192 + gi;
            int s = idx >> 5, ii = idx & 31;
            float freq = __expf(-(float)ii * (9.210340371976184f / 32.0f));
            float sn, cs;
            sincosf((float)s * freq, &sn, &cs);
            RT[idx] = (float2){cs, sn};
        }
    }
}

// ---------- fused Q/K/V projection, BM=64, A/B register prefetch ----------
__global__ __launch_bounds__(256, 5) void proj_kernel(const float* __restrict__ q,
                                                      const float* __restrict__ kv,
                                                      const short* __restrict__ Wall,
                                                      const float2* __restrict__ RT,
                                                      short* __restrict__ Qb,
                                                      short* __restrict__ Kb,
                                                      short* __restrict__ Vt) {
    __shared__ alignas(16) short As[64][72];
    __shared__ alignas(16) short Bs[64][72];
    int tid = threadIdx.x;
    int wave = tid >> 6, lane = tid & 63, quad = lane >> 4, c16 = lane & 15;
    int wm = wave >> 1, wn = wave & 1;
    int m0 = blockIdx.x * 64, n0 = blockIdx.y * 64;
    const float* A = (n0 < 256) ? q : kv;

    f32x4 acc[2][2];
    #pragma unroll
    for (int i = 0; i < 2; i++)
        #pragma unroll
        for (int j = 0; j < 2; j++) acc[i][j] = (f32x4){0.f, 0.f, 0.f, 0.f};

    float4 areg[4];
    int4 breg[2];
    #pragma unroll
    for (int i = 0; i < 4; i++) {
        int id = i * 256 + tid, r = id >> 4, ch = id & 15;
        areg[i] = *(const float4*)&A[(size_t)(m0 + r) * 1024 + ch * 4];
    }
    #pragma unroll
    for (int i = 0; i < 2; i++) {
        int id = i * 256 + tid, r = id >> 3, ch = id & 7;
        breg[i] = *(const int4*)&Wall[(size_t)(n0 + r) * 1024 + ch * 8];
    }

    for (int k0 = 0; k0 < 1024; k0 += 64) {
        __syncthreads();
        #pragma unroll
        for (int i = 0; i < 4; i++) {
            int id = i * 256 + tid, r = id >> 4, ch = id & 15;
            uint2 u;
            u.x = pk_bf16(areg[i].x, areg[i].y);
            u.y = pk_bf16(areg[i].z, areg[i].w);
            *(uint2*)&As[r][ch * 4] = u;
        }
        #pragma unroll
        for (int i = 0; i < 2; i++) {
            int id = i * 256 + tid, r = id >> 3, ch = id & 7;
            *(int4*)&Bs[r][ch * 8] = breg[i];
        }
        __syncthreads();
        if (k0 < 960) {
            #pragma unroll
            for (int i = 0; i < 4; i++) {
                int id = i * 256 + tid, r = id >> 4, ch = id & 15;
                areg[i] = *(const float4*)&A[(size_t)(m0 + r) * 1024 + k0 + 64 + ch * 4];
            }
            #pragma unroll
            for (int i = 0; i < 2; i++) {
                int id = i * 256 + tid, r = id >> 3, ch = id & 7;
                breg[i] = *(const int4*)&Wall[(size_t)(n0 + r) * 1024 + k0 + 64 + ch * 8];
            }
        }
        #pragma unroll
        for (int ks = 0; ks < 64; ks += 32) {
            bf16x8 af[2], bfr[2];
            #pragma unroll
            for (int mt = 0; mt < 2; mt++)
                af[mt] = *(const bf16x8*)&As[wm * 32 + mt * 16 + c16][ks + quad * 8];
            #pragma unroll
            for (int nt = 0; nt < 2; nt++)
                bfr[nt] = *(const bf16x8*)&Bs[wn * 32 + nt * 16 + c16][ks + quad * 8];
            #pragma unroll
            for (int mt = 0; mt < 2; mt++)
                #pragma unroll
                for (int nt = 0; nt < 2; nt++)
                    acc[mt][nt] = __builtin_amdgcn_mfma_f32_16x16x32_bf16(
                        af[mt], bfr[nt], acc[mt][nt], 0, 0, 0);
        }
    }
    __syncthreads();   // As reads done; reuse As for epilogue staging
    if (n0 < 512) {
        // Q or K: rope -> As bf16 -> coalesced stores
        #pragma unroll
        for (int mt = 0; mt < 2; mt++) {
            #pragma unroll
            for (int nt = 0; nt < 2; nt++) {
                int cl = wn * 32 + nt * 16 + c16;
                int ii = ((n0 + cl) & 63) >> 1;
                float sgn = (lane & 1) ? 1.0f : -1.0f;
                f32x4 v = acc[mt][nt];
                #pragma unroll
                for (int r = 0; r < 4; r++) {
                    int rl = wm * 32 + mt * 16 + quad * 4 + r;
                    float2 cs = RT[((m0 + rl) & (SS - 1)) * 32 + ii];
                    float other = __shfl_xor(v[r], 1);
                    As[rl][cl] = f2bf_r(v[r] * cs.x + sgn * cs.y * other);
                }
            }
        }
        __syncthreads();
        short* dstb = (n0 < 256) ? Qb : Kb;
        int nc0 = n0 & 255;
        #pragma unroll
        for (int i = 0; i < 2; i++) {
            int id = i * 256 + tid, r = id >> 3, ch = id & 7;
            *(int4*)&dstb[(size_t)(m0 + r) * 256 + nc0 + ch * 8] =
                *(const int4*)&As[r][ch * 8];
        }
    } else {
        // V: LDS transpose (As as [c][s]) -> Vt[(b*256+c)][s]
        #pragma unroll
        for (int mt = 0; mt < 2; mt++) {
            #pragma unroll
            for (int nt = 0; nt < 2; nt++) {
                int cl = wn * 32 + nt * 16 + c16;
                int sl = wm * 32 + mt * 16 + quad * 4;
                f32x4 v = acc[mt][nt];
                uint2 u;
                u.x = pk_bf16(v[0], v[1]);
                u.y = pk_bf16(v[2], v[3]);
                *(uint2*)&As[cl][sl] = u;
            }
        }
        __syncthreads();
        int b = m0 >> 11, s0 = m0 & (SS - 1), c0 = n0 - 512;
        #pragma unroll
        for (int i = 0; i < 2; i++) {
            int id = i * 256 + tid, c = id >> 3, ch = id & 7;
            *(int4*)&Vt[((size_t)(b * 256 + c0 + c)) * SS + s0 + ch * 8] =
                *(const int4*)&As[c][ch * 8];
        }
    }
}

// ---------- MFMA flash attention, static max, K-split x2, K/V reg prefetch ----------
__global__ __launch_bounds__(256, 5) void attn_kernel(const short* __restrict__ Qb,
                                                      const short* __restrict__ Kb,
                                                      const short* __restrict__ Vt,
                                                      float* __restrict__ Opart,
                                                      float* __restrict__ Lpart) {
    __shared__ alignas(16) short Qs[64][72];   // Q tile, then per-wave P tiles
    __shared__ alignas(16) short Ks[64][72], Vs[64][72];
    int tid = threadIdx.x;
    int wave = tid >> 6, lane = tid & 63, quad = lane >> 4, c16 = lane & 15;
    int qt = blockIdx.x, bh = blockIdx.y, kc = blockIdx.z;
    int q0 = qt * 64;
    size_t qkbase = (size_t)(bh >> 2) * SS * 256 + (bh & 3) * 64;
    size_t vtbase = (size_t)(bh * 64) * SS;
    size_t pbase  = (size_t)(kc * 16 + bh) * SS;

    #pragma unroll
    for (int i = 0; i < 2; i++) {
        int id = i * 256 + tid, r = id >> 3, ch = id & 7;
        *(int4*)&Qs[r][ch * 8] = *(const int4*)&Qb[qkbase + (size_t)(q0 + r) * 256 + ch * 8];
    }
    __syncthreads();
    bf16x8 aq0 = *(const bf16x8*)&Qs[wave * 16 + c16][quad * 8];
    bf16x8 aq1 = *(const bf16x8*)&Qs[wave * 16 + c16][32 + quad * 8];
    short (*Ps)[72] = (short (*)[72])Qs[wave * 16];

    float lsum[4] = {0.f, 0.f, 0.f, 0.f};
    f32x4 o[4];
    #pragma unroll
    for (int dt = 0; dt < 4; dt++) o[dt] = (f32x4){0.f, 0.f, 0.f, 0.f};

    int4 kreg[2], vreg[2];
    {
        int a0 = kc * 1024;
        #pragma unroll
        for (int i = 0; i < 2; i++) {
            int id = i * 256 + tid, r = id >> 3, ch = id & 7;
            kreg[i] = *(const int4*)&Kb[qkbase + (size_t)(a0 + r) * 256 + ch * 8];
            vreg[i] = *(const int4*)&Vt[vtbase + (size_t)r * SS + a0 + ch * 8];
        }
    }

    for (int kt = 0; kt < 16; kt++) {
        __syncthreads();
        #pragma unroll
        for (int i = 0; i < 2; i++) {
            int id = i * 256 + tid, r = id >> 3, ch = id & 7;
            *(int4*)&Ks[r][ch * 8] = kreg[i];
            *(int4*)&Vs[r][ch * 8] = vreg[i];
        }
        __syncthreads();
        if (kt < 15) {
            int a0 = kc * 1024 + (kt + 1) * 64;
            #pragma unroll
            for (int i = 0; i < 2; i++) {
                int id = i * 256 + tid, r = id >> 3, ch = id & 7;
                kreg[i] = *(const int4*)&Kb[qkbase + (size_t)(a0 + r) * 256 + ch * 8];
                vreg[i] = *(const int4*)&Vt[vtbase + (size_t)r * SS + a0 + ch * 8];
            }
        }
        f32x4 sv[4];
        #pragma unroll
        for (int nt = 0; nt < 4; nt++) sv[nt] = (f32x4){0.f, 0.f, 0.f, 0.f};
        #pragma unroll
        for (int nt = 0; nt < 4; nt++) {
            bf16x8 bk0 = *(const bf16x8*)&Ks[nt * 16 + c16][quad * 8];
            bf16x8 bk1 = *(const bf16x8*)&Ks[nt * 16 + c16][32 + quad * 8];
            sv[nt] = __builtin_amdgcn_mfma_f32_16x16x32_bf16(aq0, bk0, sv[nt], 0, 0, 0);
            sv[nt] = __builtin_amdgcn_mfma_f32_16x16x32_bf16(aq1, bk1, sv[nt], 0, 0, 0);
        }
        #pragma unroll
        for (int nt = 0; nt < 4; nt++)
            #pragma unroll
            for (int r = 0; r < 4; r++) sv[nt][r] = __builtin_exp2f(sv[nt][r]);
        #pragma unroll
        for (int r = 0; r < 4; r++)
            lsum[r] += (sv[0][r] + sv[1][r]) + (sv[2][r] + sv[3][r]);
        #pragma unroll
        for (int nt = 0; nt < 4; nt++)
            #pragma unroll
            for (int r = 0; r < 4; r++)
                Ps[quad * 4 + r][nt * 16 + c16] = f2bf_r(sv[nt][r]);
        #pragma unroll
        for (int ks = 0; ks < 64; ks += 32) {
            bf16x8 ap = *(const bf16x8*)&Ps[c16][ks + quad * 8];
            #pragma unroll
            for (int dt = 0; dt < 4; dt++) {
                bf16x8 bv = *(const bf16x8*)&Vs[dt * 16 + c16][ks + quad * 8];
                o[dt] = __builtin_amdgcn_mfma_f32_16x16x32_bf16(ap, bv, o[dt], 0, 0, 0);
            }
        }
    }
    #pragma unroll
    for (int off = 1; off < 16; off <<= 1)
        #pragma unroll
        for (int r = 0; r < 4; r++) lsum[r] += __shfl_xor(lsum[r], off);
    #pragma unroll
    for (int dt = 0; dt < 4; dt++)
        #pragma unroll
        for (int r = 0; r < 4; r++) {
            int row = q0 + wave * 16 + quad * 4 + r;
            Opart[(pbase + row) * 64 + dt * 16 + c16] = o[dt][r];
        }
    if (c16 == 0)
        #pragma unroll
        for (int r = 0; r < 4; r++)
            Lpart[pbase + q0 + wave * 16 + quad * 4 + r] = lsum[r];
}

// ---------- output projection, BM=64 BN=128, fused K-split combine ----------
__global__ __launch_bounds__(256) void outproj_kernel(const float* __restrict__ Op,
                                                      const float* __restrict__ Lp,
                                                      const short* __restrict__ Wo4,
                                                      float* __restrict__ out) {
    __shared__ alignas(16) short As[64][72];
    __shared__ alignas(16) short Bs[128][72];
    int tid = threadIdx.x;
    int wave = tid >> 6, lane = tid & 63, quad = lane >> 4, c16 = lane & 15;
    int wm = wave >> 1, wn = wave & 1;
    int m0 = blockIdx.x * 64, n0 = blockIdx.y * 128;

    f32x4 acc[2][4];
    #pragma unroll
    for (int i = 0; i < 2; i++)
        #pragma unroll
        for (int j = 0; j < 4; j++) acc[i][j] = (f32x4){0.f, 0.f, 0.f, 0.f};

    for (int k0 = 0; k0 < 256; k0 += 64) {
        int h = k0 >> 6;
        #pragma unroll
        for (int i = 0; i < 4; i++) {
            int id = i * 256 + tid, r = id >> 4, ch = id & 15;
            int row = m0 + r, b = row >> 11, s = row & (SS - 1);
            int bh = b * 4 + h;
            size_t pidx = ((size_t)bh * SS + s) * 64 + ch * 4;
            float4 a = *(const float4*)&Op[pidx];
            float4 c = *(const float4*)&Op[pidx + (size_t)16 * SS * 64];
            float l = Lp[(size_t)bh * SS + s] + Lp[(size_t)(16 + bh) * SS + s];
            float rl = __builtin_amdgcn_rcpf(l);
            uint2 u;
            u.x = pk_bf16((a.x + c.x) * rl, (a.y + c.y) * rl);
            u.y = pk_bf16((a.z + c.z) * rl, (a.w + c.w) * rl);
            *(uint2*)&As[r][ch * 4] = u;
        }
        #pragma unroll
        for (int i = 0; i < 4; i++) {
            int id = i * 256 + tid, r = id >> 3, ch = id & 7;
            *(int4*)&Bs[r][ch * 8] =
                *(const int4*)&Wo4[(size_t)(n0 + r) * 256 + k0 + ch * 8];
        }
        __syncthreads();
        #pragma unroll
        for (int ks = 0; ks < 64; ks += 32) {
            bf16x8 af[2], bfr[4];
            #pragma unroll
            for (int mt = 0; mt < 2; mt++)
                af[mt] = *(const bf16x8*)&As[wm * 32 + mt * 16 + c16][ks + quad * 8];
            #pragma unroll
            for (int nt = 0; nt < 4; nt++)
                bfr[nt] = *(const bf16x8*)&Bs[wn * 64 + nt * 16 + c16][ks + quad * 8];
            #pragma unroll
            for (int mt = 0; mt < 2; mt++)
                #pragma unroll
                for (int nt = 0; nt < 4; nt++)
                    acc[mt][nt] = __builtin_amdgcn_mfma_f32_16x16x32_bf16(
                        af[mt], bfr[nt], acc[mt][nt], 0, 0, 0);
        }
        __syncthreads();
    }
    #pragma unroll
    for (int mt = 0; mt < 2; mt++)
        #pragma unroll
        for (int nt = 0; nt < 4; nt++) {
            int col = n0 + wn * 64 + nt * 16 + c16;
            int rowb = m0 + wm * 32 + mt * 16 + quad * 4;
            #pragma unroll
            for (int r = 0; r < 4; r++)
                out[(size_t)(rowb + r) * 1024 + col] = acc[mt][nt][r];
        }
}

extern "C" void kernel_launch(void* const* d_in, const int* in_sizes, int n_in,
                              void* d_out, int out_size, void* d_ws, size_t ws_size,
                              hipStream_t stream) {
    const float* q  = (const float*)d_in[0];
    const float* kv = (const float*)d_in[1];
    const float* Wq = (const float*)d_in[2];
    const float* Wk = (const float*)d_in[3];
    const float* Wv = (const float*)d_in[4];
    const float* Wo = (const float*)d_in[5];
    float* out = (float*)d_out;

    short* Qb    = (short*)d_ws;           // 2097152 bf16
    short* Kb    = Qb + 2097152;           // 2097152
    short* Vt    = Kb + 2097152;           // 2097152 (pre-transposed [b*256+h*64+d][s])
    short* Wall  = Vt + 2097152;           // 786432
    short* Wo4   = Wall + 786432;          // 262144
    float2* RT   = (float2*)(Wo4 + 262144);    // 65536 float2
    float* Opart = (float*)(RT + 65536);   // 4194304 fp32
    float* Lpart = Opart + 4194304;        // 65536 fp32

    prep_kernel<<<240, 256, 0, stream>>>(Wq, Wk, Wv, Wo, Wall, Wo4, RT);

    proj_kernel<<<dim3(128, 12), 256, 0, stream>>>(q, kv, Wall, RT, Qb, Kb, Vt);

    attn_kernel<<<dim3(32, 16, 2), 256, 0, stream>>>(Qb, Kb, Vt, Opart, Lpart);

    outproj_kernel<<<dim3(128, 8), 256, 0, stream>>>(Opart, Lpart, Wo4, out);
}

// Round 8
// 261.595 us; speedup vs baseline: 1.1126x; 1.1126x over previous
//
#include <hip/hip_runtime.h>
#include <math.h>

#define SS 2048
#define EE 1024
#define PAD 68   // 136B rows: bank step 2/row -> <=2-way conflicts (free)

using bf16x8 = __attribute__((ext_vector_type(8))) short;
using f32x4  = __attribute__((ext_vector_type(4))) float;

// round-half-up, 2 VALU
__device__ inline short f2bf_r(float x) {
    return (short)((__builtin_bit_cast(unsigned, x) + 0x8000u) >> 16);
}
// pack 2 floats -> 2 bf16 in one dword: 2 adds + 1 v_perm
__device__ inline unsigned pk_bf16(float a, float b) {
    unsigned ua = __builtin_bit_cast(unsigned, a) + 0x8000u;
    unsigned ub = __builtin_bit_cast(unsigned, b) + 0x8000u;
    return __builtin_amdgcn_perm(ub, ua, 0x07060302u);
}

// ---------- weight prep: LDS-tiled coalesced transposes + rope table ----------
__global__ __launch_bounds__(256) void prep_kernel(const float* __restrict__ Wq,
                                                   const float* __restrict__ Wk,
                                                   const float* __restrict__ Wv,
                                                   const float* __restrict__ Wo,
                                                   short* __restrict__ Wall,
                                                   short* __restrict__ Wo4,
                                                   float2* __restrict__ RT) {
    __shared__ float T[64][65];
    int bid = blockIdx.x, tid = threadIdx.x;
    if (bid < 192) {
        int src = bid >> 6;            // 0=Wq(sum+scale) 1=Wk 2=Wv
        int j = bid & 63;
        int et = j & 15, ct = j >> 4;
        int e0 = et * 64, c0 = ct * 64;
        #pragma unroll
        for (int p = 0; p < 4; p++) {
            int el = p * 16 + (tid >> 4);
            int c4 = (tid & 15) * 4;
            float4 v;
            if (src == 0) {
                float4 s = {0, 0, 0, 0};
                #pragma unroll
                for (int g = 0; g < 4; g++) {
                    float4 w = *(const float4*)&Wq[(size_t)(e0 + el) * 1024 + ct * 256 + g * 64 + c4];
                    s.x += w.x; s.y += w.y; s.z += w.z; s.w += w.w;
                }
                v.x = s.x * 0.18033688011112042f; v.y = s.y * 0.18033688011112042f;
                v.z = s.z * 0.18033688011112042f; v.w = s.w * 0.18033688011112042f;
            } else if (src == 1) {
                v = *(const float4*)&Wk[(size_t)(e0 + el) * 256 + c0 + c4];
            } else {
                v = *(const float4*)&Wv[(size_t)(e0 + el) * 256 + c0 + c4];
            }
            T[c4][el] = v.x; T[c4 + 1][el] = v.y; T[c4 + 2][el] = v.z; T[c4 + 3][el] = v.w;
        }
        __syncthreads();
        #pragma unroll
        for (int p = 0; p < 8; p++) {
            int c = p * 8 + (tid >> 5);
            int e2 = (tid & 31) * 2;
            unsigned u = pk_bf16(T[c][e2], T[c][e2 + 1]);
            *(unsigned*)&Wall[(size_t)(src * 256 + c0 + c) * 1024 + e0 + e2] = u;
        }
    } else if (bid < 208) {
        int e0 = (bid - 192) * 64;
        #pragma unroll
        for (int p = 0; p < 4; p++) {
            int d = p * 16 + (tid >> 4);
            int e4 = (tid & 15) * 4;
            float4 v = *(const float4*)&Wo[(size_t)d * 1024 + e0 + e4];
            T[e4][d] = v.x; T[e4 + 1][d] = v.y; T[e4 + 2][d] = v.z; T[e4 + 3][d] = v.w;
        }
        __syncthreads();
        #pragma unroll
        for (int p = 0; p < 8; p++) {
            int e = p * 8 + (tid >> 5);
            int d2 = (tid & 31) * 2;
            unsigned u = pk_bf16(0.25f * T[e][d2], 0.25f * T[e][d2 + 1]);
            #pragma unroll
            for (int h = 0; h < 4; h++)
                *(unsigned*)&Wo4[(size_t)(e0 + e) * 256 + h * 64 + d2] = u;
        }
    } else {
        int gi = (bid - 208) * 256 + tid;
        #pragma unroll
        for (int u = 0; u < 8; u++) {
            int idx = u * 8192 + gi;
            int s = idx >> 5, ii = idx & 31;
            float freq = __expf(-(float)ii * (9.210340371976184f / 32.0f));
            float sn, cs;
            sincosf((float)s * freq, &sn, &cs);
            RT[idx] = (float2){cs, sn};
        }
    }
}

// ---------- fused Q/K/V projection, BM=64, direct staging (NO reg prefetch) ----------
__global__ __launch_bounds__(256) void proj_kernel(const float* __restrict__ q,
                                                   const float* __restrict__ kv,
                                                   const short* __restrict__ Wall,
                                                   const float2* __restrict__ RT,
                                                   short* __restrict__ Qb,
                                                   short* __restrict__ Kb,
                                                   short* __restrict__ Vt) {
    __shared__ alignas(16) short As[64][PAD];
    __shared__ alignas(16) short Bs[64][PAD];
    int tid = threadIdx.x;
    int wave = tid >> 6, lane = tid & 63, quad = lane >> 4, c16 = lane & 15;
    int wm = wave >> 1, wn = wave & 1;
    int m0 = blockIdx.x * 64, n0 = blockIdx.y * 64;
    const float* A = (n0 < 256) ? q : kv;

    f32x4 acc[2][2];
    #pragma unroll
    for (int i = 0; i < 2; i++)
        #pragma unroll
        for (int j = 0; j < 2; j++) acc[i][j] = (f32x4){0.f, 0.f, 0.f, 0.f};

    for (int k0 = 0; k0 < 1024; k0 += 64) {
        #pragma unroll
        for (int i = 0; i < 4; i++) {
            int id = i * 256 + tid, r = id >> 4, ch = id & 15;
            float4 v = *(const float4*)&A[(size_t)(m0 + r) * 1024 + k0 + ch * 4];
            uint2 u;
            u.x = pk_bf16(v.x, v.y);
            u.y = pk_bf16(v.z, v.w);
            *(uint2*)&As[r][ch * 4] = u;
        }
        #pragma unroll
        for (int i = 0; i < 2; i++) {
            int id = i * 256 + tid, r = id >> 3, ch = id & 7;
            *(int4*)&Bs[r][ch * 8] =
                *(const int4*)&Wall[(size_t)(n0 + r) * 1024 + k0 + ch * 8];
        }
        __syncthreads();
        #pragma unroll
        for (int ks = 0; ks < 64; ks += 32) {
            bf16x8 af[2], bfr[2];
            #pragma unroll
            for (int mt = 0; mt < 2; mt++)
                af[mt] = *(const bf16x8*)&As[wm * 32 + mt * 16 + c16][ks + quad * 8];
            #pragma unroll
            for (int nt = 0; nt < 2; nt++)
                bfr[nt] = *(const bf16x8*)&Bs[wn * 32 + nt * 16 + c16][ks + quad * 8];
            #pragma unroll
            for (int mt = 0; mt < 2; mt++)
                #pragma unroll
                for (int nt = 0; nt < 2; nt++)
                    acc[mt][nt] = __builtin_amdgcn_mfma_f32_16x16x32_bf16(
                        af[mt], bfr[nt], acc[mt][nt], 0, 0, 0);
        }
        __syncthreads();
    }
    if (n0 < 512) {
        // Q or K: rope -> As bf16 -> coalesced stores
        #pragma unroll
        for (int mt = 0; mt < 2; mt++) {
            #pragma unroll
            for (int nt = 0; nt < 2; nt++) {
                int cl = wn * 32 + nt * 16 + c16;
                int ii = ((n0 + cl) & 63) >> 1;
                float sgn = (lane & 1) ? 1.0f : -1.0f;
                f32x4 v = acc[mt][nt];
                #pragma unroll
                for (int r = 0; r < 4; r++) {
                    int rl = wm * 32 + mt * 16 + quad * 4 + r;
                    float2 cs = RT[((m0 + rl) & (SS - 1)) * 32 + ii];
                    float other = __shfl_xor(v[r], 1);
                    As[rl][cl] = f2bf_r(v[r] * cs.x + sgn * cs.y * other);
                }
            }
        }
        __syncthreads();
        short* dstb = (n0 < 256) ? Qb : Kb;
        int nc0 = n0 & 255;
        #pragma unroll
        for (int i = 0; i < 2; i++) {
            int id = i * 256 + tid, r = id >> 3, ch = id & 7;
            *(int4*)&dstb[(size_t)(m0 + r) * 256 + nc0 + ch * 8] =
                *(const int4*)&As[r][ch * 8];
        }
    } else {
        // V: LDS transpose (As as [c][s]) -> Vt[(b*256+c)][s]
        #pragma unroll
        for (int mt = 0; mt < 2; mt++) {
            #pragma unroll
            for (int nt = 0; nt < 2; nt++) {
                int cl = wn * 32 + nt * 16 + c16;
                int sl = wm * 32 + mt * 16 + quad * 4;
                f32x4 v = acc[mt][nt];
                uint2 u;
                u.x = pk_bf16(v[0], v[1]);
                u.y = pk_bf16(v[2], v[3]);
                *(uint2*)&As[cl][sl] = u;
            }
        }
        __syncthreads();
        int b = m0 >> 11, s0 = m0 & (SS - 1), c0 = n0 - 512;
        #pragma unroll
        for (int i = 0; i < 2; i++) {
            int id = i * 256 + tid, c = id >> 3, ch = id & 7;
            *(int4*)&Vt[((size_t)(b * 256 + c0 + c)) * SS + s0 + ch * 8] =
                *(const int4*)&As[c][ch * 8];
        }
    }
}

// ---------- MFMA flash attention, static max, K-split x2, K/V reg prefetch ----------
__global__ __launch_bounds__(256) void attn_kernel(const short* __restrict__ Qb,
                                                   const short* __restrict__ Kb,
                                                   const short* __restrict__ Vt,
                                                   float* __restrict__ Opart,
                                                   float* __restrict__ Lpart) {
    __shared__ alignas(16) short Qs[64][PAD];   // Q tile, then per-wave P tiles
    __shared__ alignas(16) short Ks[64][PAD], Vs[64][PAD];
    int tid = threadIdx.x;
    int wave = tid >> 6, lane = tid & 63, quad = lane >> 4, c16 = lane & 15;
    int qt = blockIdx.x, bh = blockIdx.y, kc = blockIdx.z;
    int q0 = qt * 64;
    size_t qkbase = (size_t)(bh >> 2) * SS * 256 + (bh & 3) * 64;
    size_t vtbase = (size_t)(bh * 64) * SS;
    size_t pbase  = (size_t)(kc * 16 + bh) * SS;

    #pragma unroll
    for (int i = 0; i < 2; i++) {
        int id = i * 256 + tid, r = id >> 3, ch = id & 7;
        *(int4*)&Qs[r][ch * 8] = *(const int4*)&Qb[qkbase + (size_t)(q0 + r) * 256 + ch * 8];
    }
    __syncthreads();
    bf16x8 aq0 = *(const bf16x8*)&Qs[wave * 16 + c16][quad * 8];
    bf16x8 aq1 = *(const bf16x8*)&Qs[wave * 16 + c16][32 + quad * 8];
    short (*Ps)[PAD] = (short (*)[PAD])Qs[wave * 16];

    float lsum[4] = {0.f, 0.f, 0.f, 0.f};
    f32x4 o[4];
    #pragma unroll
    for (int dt = 0; dt < 4; dt++) o[dt] = (f32x4){0.f, 0.f, 0.f, 0.f};

    int4 kreg[2], vreg[2];
    {
        int a0 = kc * 1024;
        #pragma unroll
        for (int i = 0; i < 2; i++) {
            int id = i * 256 + tid, r = id >> 3, ch = id & 7;
            kreg[i] = *(const int4*)&Kb[qkbase + (size_t)(a0 + r) * 256 + ch * 8];
            vreg[i] = *(const int4*)&Vt[vtbase + (size_t)r * SS + a0 + ch * 8];
        }
    }

    for (int kt = 0; kt < 16; kt++) {
        __syncthreads();
        #pragma unroll
        for (int i = 0; i < 2; i++) {
            int id = i * 256 + tid, r = id >> 3, ch = id & 7;
            *(int4*)&Ks[r][ch * 8] = kreg[i];
            *(int4*)&Vs[r][ch * 8] = vreg[i];
        }
        __syncthreads();
        if (kt < 15) {
            int a0 = kc * 1024 + (kt + 1) * 64;
            #pragma unroll
            for (int i = 0; i < 2; i++) {
                int id = i * 256 + tid, r = id >> 3, ch = id & 7;
                kreg[i] = *(const int4*)&Kb[qkbase + (size_t)(a0 + r) * 256 + ch * 8];
                vreg[i] = *(const int4*)&Vt[vtbase + (size_t)r * SS + a0 + ch * 8];
            }
        }
        f32x4 sv[4];
        #pragma unroll
        for (int nt = 0; nt < 4; nt++) sv[nt] = (f32x4){0.f, 0.f, 0.f, 0.f};
        #pragma unroll
        for (int nt = 0; nt < 4; nt++) {
            bf16x8 bk0 = *(const bf16x8*)&Ks[nt * 16 + c16][quad * 8];
            bf16x8 bk1 = *(const bf16x8*)&Ks[nt * 16 + c16][32 + quad * 8];
            sv[nt] = __builtin_amdgcn_mfma_f32_16x16x32_bf16(aq0, bk0, sv[nt], 0, 0, 0);
            sv[nt] = __builtin_amdgcn_mfma_f32_16x16x32_bf16(aq1, bk1, sv[nt], 0, 0, 0);
        }
        #pragma unroll
        for (int nt = 0; nt < 4; nt++)
            #pragma unroll
            for (int r = 0; r < 4; r++) sv[nt][r] = __builtin_exp2f(sv[nt][r]);
        #pragma unroll
        for (int r = 0; r < 4; r++)
            lsum[r] += (sv[0][r] + sv[1][r]) + (sv[2][r] + sv[3][r]);
        #pragma unroll
        for (int nt = 0; nt < 4; nt++)
            #pragma unroll
            for (int r = 0; r < 4; r++)
                Ps[quad * 4 + r][nt * 16 + c16] = f2bf_r(sv[nt][r]);
        #pragma unroll
        for (int ks = 0; ks < 64; ks += 32) {
            bf16x8 ap = *(const bf16x8*)&Ps[c16][ks + quad * 8];
            #pragma unroll
            for (int dt = 0; dt < 4; dt++) {
                bf16x8 bv = *(const bf16x8*)&Vs[dt * 16 + c16][ks + quad * 8];
                o[dt] = __builtin_amdgcn_mfma_f32_16x16x32_bf16(ap, bv, o[dt], 0, 0, 0);
            }
        }
    }
    #pragma unroll
    for (int off = 1; off < 16; off <<= 1)
        #pragma unroll
        for (int r = 0; r < 4; r++) lsum[r] += __shfl_xor(lsum[r], off);
    #pragma unroll
    for (int dt = 0; dt < 4; dt++)
        #pragma unroll
        for (int r = 0; r < 4; r++) {
            int row = q0 + wave * 16 + quad * 4 + r;
            Opart[(pbase + row) * 64 + dt * 16 + c16] = o[dt][r];
        }
    if (c16 == 0)
        #pragma unroll
        for (int r = 0; r < 4; r++)
            Lpart[pbase + q0 + wave * 16 + quad * 4 + r] = lsum[r];
}

// ---------- output projection, BM=64 BN=128, fused K-split combine ----------
__global__ __launch_bounds__(256) void outproj_kernel(const float* __restrict__ Op,
                                                      const float* __restrict__ Lp,
                                                      const short* __restrict__ Wo4,
                                                      float* __restrict__ out) {
    __shared__ alignas(16) short As[64][72];
    __shared__ alignas(16) short Bs[128][72];
    int tid = threadIdx.x;
    int wave = tid >> 6, lane = tid & 63, quad = lane >> 4, c16 = lane & 15;
    int wm = wave >> 1, wn = wave & 1;
    int m0 = blockIdx.x * 64, n0 = blockIdx.y * 128;

    f32x4 acc[2][4];
    #pragma unroll
    for (int i = 0; i < 2; i++)
        #pragma unroll
        for (int j = 0; j < 4; j++) acc[i][j] = (f32x4){0.f, 0.f, 0.f, 0.f};

    for (int k0 = 0; k0 < 256; k0 += 64) {
        int h = k0 >> 6;
        #pragma unroll
        for (int i = 0; i < 4; i++) {
            int id = i * 256 + tid, r = id >> 4, ch = id & 15;
            int row = m0 + r, b = row >> 11, s = row & (SS - 1);
            int bh = b * 4 + h;
            size_t pidx = ((size_t)bh * SS + s) * 64 + ch * 4;
            float4 a = *(const float4*)&Op[pidx];
            float4 c = *(const float4*)&Op[pidx + (size_t)16 * SS * 64];
            float l = Lp[(size_t)bh * SS + s] + Lp[(size_t)(16 + bh) * SS + s];
            float rl = __builtin_amdgcn_rcpf(l);
            uint2 u;
            u.x = pk_bf16((a.x + c.x) * rl, (a.y + c.y) * rl);
            u.y = pk_bf16((a.z + c.z) * rl, (a.w + c.w) * rl);
            *(uint2*)&As[r][ch * 4] = u;
        }
        #pragma unroll
        for (int i = 0; i < 4; i++) {
            int id = i * 256 + tid, r = id >> 3, ch = id & 7;
            *(int4*)&Bs[r][ch * 8] =
                *(const int4*)&Wo4[(size_t)(n0 + r) * 256 + k0 + ch * 8];
        }
        __syncthreads();
        #pragma unroll
        for (int ks = 0; ks < 64; ks += 32) {
            bf16x8 af[2], bfr[4];
            #pragma unroll
            for (int mt = 0; mt < 2; mt++)
                af[mt] = *(const bf16x8*)&As[wm * 32 + mt * 16 + c16][ks + quad * 8];
            #pragma unroll
            for (int nt = 0; nt < 4; nt++)
                bfr[nt] = *(const bf16x8*)&Bs[wn * 64 + nt * 16 + c16][ks + quad * 8];
            #pragma unroll
            for (int mt = 0; mt < 2; mt++)
                #pragma unroll
                for (int nt = 0; nt < 4; nt++)
                    acc[mt][nt] = __builtin_amdgcn_mfma_f32_16x16x32_bf16(
                        af[mt], bfr[nt], acc[mt][nt], 0, 0, 0);
        }
        __syncthreads();
    }
    #pragma unroll
    for (int mt = 0; mt < 2; mt++)
        #pragma unroll
        for (int nt = 0; nt < 4; nt++) {
            int col = n0 + wn * 64 + nt * 16 + c16;
            int rowb = m0 + wm * 32 + mt * 16 + quad * 4;
            #pragma unroll
            for (int r = 0; r < 4; r++)
                out[(size_t)(rowb + r) * 1024 + col] = acc[mt][nt][r];
        }
}

extern "C" void kernel_launch(void* const* d_in, const int* in_sizes, int n_in,
                              void* d_out, int out_size, void* d_ws, size_t ws_size,
                              hipStream_t stream) {
    const float* q  = (const float*)d_in[0];
    const float* kv = (const float*)d_in[1];
    const float* Wq = (const float*)d_in[2];
    const float* Wk = (const float*)d_in[3];
    const float* Wv = (const float*)d_in[4];
    const float* Wo = (const float*)d_in[5];
    float* out = (float*)d_out;

    short* Qb    = (short*)d_ws;           // 2097152 bf16
    short* Kb    = Qb + 2097152;           // 2097152
    short* Vt    = Kb + 2097152;           // 2097152 (pre-transposed [b*256+h*64+d][s])
    short* Wall  = Vt + 2097152;           // 786432
    short* Wo4   = Wall + 786432;          // 262144
    float2* RT   = (float2*)(Wo4 + 262144);    // 65536 float2
    float* Opart = (float*)(RT + 65536);   // 4194304 fp32
    float* Lpart = Opart + 4194304;        // 65536 fp32

    prep_kernel<<<240, 256, 0, stream>>>(Wq, Wk, Wv, Wo, Wall, Wo4, RT);

    proj_kernel<<<dim3(128, 12), 256, 0, stream>>>(q, kv, Wall, RT, Qb, Kb, Vt);

    attn_kernel<<<dim3(32, 16, 2), 256, 0, stream>>>(Qb, Kb, Vt, Opart, Lpart);

    outproj_kernel<<<dim3(128, 8), 256, 0, stream>>>(Opart, Lpart, Wo4, out);
}

// Round 9
// 229.977 us; speedup vs baseline: 1.2656x; 1.1375x over previous
//
#include <hip/hip_runtime.h>
#include <math.h>

#define SS 2048
#define EE 1024
#define PAD 68   // 136B rows: bank step 2/row -> <=2-way conflicts (free)

using bf16x8 = __attribute__((ext_vector_type(8))) short;
using f32x4  = __attribute__((ext_vector_type(4))) float;

// round-half-up, 2 VALU
__device__ inline short f2bf_r(float x) {
    return (short)((__builtin_bit_cast(unsigned, x) + 0x8000u) >> 16);
}
// pack 2 floats -> 2 bf16 in one dword: 2 adds + 1 v_perm
__device__ inline unsigned pk_bf16(float a, float b) {
    unsigned ua = __builtin_bit_cast(unsigned, a) + 0x8000u;
    unsigned ub = __builtin_bit_cast(unsigned, b) + 0x8000u;
    return __builtin_amdgcn_perm(ub, ua, 0x07060302u);
}

// ---------- weight prep: LDS-tiled coalesced transposes + rope table ----------
__global__ __launch_bounds__(256) void prep_kernel(const float* __restrict__ Wq,
                                                   const float* __restrict__ Wk,
                                                   const float* __restrict__ Wv,
                                                   const float* __restrict__ Wo,
                                                   short* __restrict__ Wall,
                                                   short* __restrict__ Wo4,
                                                   float2* __restrict__ RT) {
    __shared__ float T[64][65];
    int bid = blockIdx.x, tid = threadIdx.x;
    if (bid < 192) {
        int src = bid >> 6;            // 0=Wq(sum+scale) 1=Wk 2=Wv
        int j = bid & 63;
        int et = j & 15, ct = j >> 4;
        int e0 = et * 64, c0 = ct * 64;
        #pragma unroll
        for (int p = 0; p < 4; p++) {
            int el = p * 16 + (tid >> 4);
            int c4 = (tid & 15) * 4;
            float4 v;
            if (src == 0) {
                float4 s = {0, 0, 0, 0};
                #pragma unroll
                for (int g = 0; g < 4; g++) {
                    float4 w = *(const float4*)&Wq[(size_t)(e0 + el) * 1024 + ct * 256 + g * 64 + c4];
                    s.x += w.x; s.y += w.y; s.z += w.z; s.w += w.w;
                }
                v.x = s.x * 0.18033688011112042f; v.y = s.y * 0.18033688011112042f;
                v.z = s.z * 0.18033688011112042f; v.w = s.w * 0.18033688011112042f;
            } else if (src == 1) {
                v = *(const float4*)&Wk[(size_t)(e0 + el) * 256 + c0 + c4];
            } else {
                v = *(const float4*)&Wv[(size_t)(e0 + el) * 256 + c0 + c4];
            }
            T[c4][el] = v.x; T[c4 + 1][el] = v.y; T[c4 + 2][el] = v.z; T[c4 + 3][el] = v.w;
        }
        __syncthreads();
        #pragma unroll
        for (int p = 0; p < 8; p++) {
            int c = p * 8 + (tid >> 5);
            int e2 = (tid & 31) * 2;
            unsigned u = pk_bf16(T[c][e2], T[c][e2 + 1]);
            *(unsigned*)&Wall[(size_t)(src * 256 + c0 + c) * 1024 + e0 + e2] = u;
        }
    } else if (bid < 208) {
        int e0 = (bid - 192) * 64;
        #pragma unroll
        for (int p = 0; p < 4; p++) {
            int d = p * 16 + (tid >> 4);
            int e4 = (tid & 15) * 4;
            float4 v = *(const float4*)&Wo[(size_t)d * 1024 + e0 + e4];
            T[e4][d] = v.x; T[e4 + 1][d] = v.y; T[e4 + 2][d] = v.z; T[e4 + 3][d] = v.w;
        }
        __syncthreads();
        #pragma unroll
        for (int p = 0; p < 8; p++) {
            int e = p * 8 + (tid >> 5);
            int d2 = (tid & 31) * 2;
            unsigned u = pk_bf16(0.25f * T[e][d2], 0.25f * T[e][d2 + 1]);
            #pragma unroll
            for (int h = 0; h < 4; h++)
                *(unsigned*)&Wo4[(size_t)(e0 + e) * 256 + h * 64 + d2] = u;
        }
    } else {
        int gi = (bid - 208) * 256 + tid;
        #pragma unroll
        for (int u = 0; u < 8; u++) {
            int idx = u * 8192 + gi;
            int s = idx >> 5, ii = idx & 31;
            float freq = __expf(-(float)ii * (9.210340371976184f / 32.0f));
            float sn, cs;
            sincosf((float)s * freq, &sn, &cs);
            RT[idx] = (float2){cs, sn};
        }
    }
}

// ---------- fused Q/K/V projection, BM=64, direct staging ----------
__global__ __launch_bounds__(256) void proj_kernel(const float* __restrict__ q,
                                                   const float* __restrict__ kv,
                                                   const short* __restrict__ Wall,
                                                   const float2* __restrict__ RT,
                                                   short* __restrict__ Qb,
                                                   short* __restrict__ Kb,
                                                   short* __restrict__ Vt) {
    __shared__ alignas(16) short As[64][PAD];
    __shared__ alignas(16) short Bs[64][PAD];
    int tid = threadIdx.x;
    int wave = tid >> 6, lane = tid & 63, quad = lane >> 4, c16 = lane & 15;
    int wm = wave >> 1, wn = wave & 1;
    int m0 = blockIdx.x * 64, n0 = blockIdx.y * 64;
    const float* A = (n0 < 256) ? q : kv;

    f32x4 acc[2][2];
    #pragma unroll
    for (int i = 0; i < 2; i++)
        #pragma unroll
        for (int j = 0; j < 2; j++) acc[i][j] = (f32x4){0.f, 0.f, 0.f, 0.f};

    for (int k0 = 0; k0 < 1024; k0 += 64) {
        #pragma unroll
        for (int i = 0; i < 4; i++) {
            int id = i * 256 + tid, r = id >> 4, ch = id & 15;
            float4 v = *(const float4*)&A[(size_t)(m0 + r) * 1024 + k0 + ch * 4];
            uint2 u;
            u.x = pk_bf16(v.x, v.y);
            u.y = pk_bf16(v.z, v.w);
            *(uint2*)&As[r][ch * 4] = u;
        }
        #pragma unroll
        for (int i = 0; i < 2; i++) {
            int id = i * 256 + tid, r = id >> 3, ch = id & 7;
            *(int4*)&Bs[r][ch * 8] =
                *(const int4*)&Wall[(size_t)(n0 + r) * 1024 + k0 + ch * 8];
        }
        __syncthreads();
        #pragma unroll
        for (int ks = 0; ks < 64; ks += 32) {
            bf16x8 af[2], bfr[2];
            #pragma unroll
            for (int mt = 0; mt < 2; mt++)
                af[mt] = *(const bf16x8*)&As[wm * 32 + mt * 16 + c16][ks + quad * 8];
            #pragma unroll
            for (int nt = 0; nt < 2; nt++)
                bfr[nt] = *(const bf16x8*)&Bs[wn * 32 + nt * 16 + c16][ks + quad * 8];
            #pragma unroll
            for (int mt = 0; mt < 2; mt++)
                #pragma unroll
                for (int nt = 0; nt < 2; nt++)
                    acc[mt][nt] = __builtin_amdgcn_mfma_f32_16x16x32_bf16(
                        af[mt], bfr[nt], acc[mt][nt], 0, 0, 0);
        }
        __syncthreads();
    }
    if (n0 < 512) {
        // Q or K: rope -> As bf16 -> coalesced stores
        #pragma unroll
        for (int mt = 0; mt < 2; mt++) {
            #pragma unroll
            for (int nt = 0; nt < 2; nt++) {
                int cl = wn * 32 + nt * 16 + c16;
                int ii = ((n0 + cl) & 63) >> 1;
                float sgn = (lane & 1) ? 1.0f : -1.0f;
                f32x4 v = acc[mt][nt];
                #pragma unroll
                for (int r = 0; r < 4; r++) {
                    int rl = wm * 32 + mt * 16 + quad * 4 + r;
                    float2 cs = RT[((m0 + rl) & (SS - 1)) * 32 + ii];
                    float other = __shfl_xor(v[r], 1);
                    As[rl][cl] = f2bf_r(v[r] * cs.x + sgn * cs.y * other);
                }
            }
        }
        __syncthreads();
        short* dstb = (n0 < 256) ? Qb : Kb;
        int nc0 = n0 & 255;
        #pragma unroll
        for (int i = 0; i < 2; i++) {
            int id = i * 256 + tid, r = id >> 3, ch = id & 7;
            *(int4*)&dstb[(size_t)(m0 + r) * 256 + nc0 + ch * 8] =
                *(const int4*)&As[r][ch * 8];
        }
    } else {
        // V: LDS transpose (As as [c][s]) -> Vt[(b*256+c)][s]
        #pragma unroll
        for (int mt = 0; mt < 2; mt++) {
            #pragma unroll
            for (int nt = 0; nt < 2; nt++) {
                int cl = wn * 32 + nt * 16 + c16;
                int sl = wm * 32 + mt * 16 + quad * 4;
                f32x4 v = acc[mt][nt];
                uint2 u;
                u.x = pk_bf16(v[0], v[1]);
                u.y = pk_bf16(v[2], v[3]);
                *(uint2*)&As[cl][sl] = u;
            }
        }
        __syncthreads();
        int b = m0 >> 11, s0 = m0 & (SS - 1), c0 = n0 - 512;
        #pragma unroll
        for (int i = 0; i < 2; i++) {
            int id = i * 256 + tid, c = id >> 3, ch = id & 7;
            *(int4*)&Vt[((size_t)(b * 256 + c0 + c)) * SS + s0 + ch * 8] =
                *(const int4*)&As[c][ch * 8];
        }
    }
}

// ---------- MFMA flash attention: static max, K-split x2, LDS double-buffer ----------
// 1 barrier/iter; kt+1 loads issued at iter top, covered by compute, ds_write'd
// to the other buffer before the barrier (no registers live across a barrier).
__global__ __launch_bounds__(256) void attn_kernel(const short* __restrict__ Qb,
                                                   const short* __restrict__ Kb,
                                                   const short* __restrict__ Vt,
                                                   float* __restrict__ Opart,
                                                   float* __restrict__ Lpart) {
    __shared__ alignas(16) short Qs[64][PAD];           // Q tile, then per-wave P tiles
    __shared__ alignas(16) short Ks[2][64][PAD], Vs[2][64][PAD];
    int tid = threadIdx.x;
    int wave = tid >> 6, lane = tid & 63, quad = lane >> 4, c16 = lane & 15;
    int qt = blockIdx.x, bh = blockIdx.y, kc = blockIdx.z;
    int q0 = qt * 64;
    size_t qkbase = (size_t)(bh >> 2) * SS * 256 + (bh & 3) * 64;
    size_t vtbase = (size_t)(bh * 64) * SS;
    size_t pbase  = (size_t)(kc * 16 + bh) * SS;

    // stage Q + K/V tile 0, single barrier
    #pragma unroll
    for (int i = 0; i < 2; i++) {
        int id = i * 256 + tid, r = id >> 3, ch = id & 7;
        *(int4*)&Qs[r][ch * 8] = *(const int4*)&Qb[qkbase + (size_t)(q0 + r) * 256 + ch * 8];
        int a0 = kc * 1024;
        *(int4*)&Ks[0][r][ch * 8] =
            *(const int4*)&Kb[qkbase + (size_t)(a0 + r) * 256 + ch * 8];
        *(int4*)&Vs[0][r][ch * 8] =
            *(const int4*)&Vt[vtbase + (size_t)r * SS + a0 + ch * 8];
    }
    __syncthreads();
    bf16x8 aq0 = *(const bf16x8*)&Qs[wave * 16 + c16][quad * 8];
    bf16x8 aq1 = *(const bf16x8*)&Qs[wave * 16 + c16][32 + quad * 8];
    short (*Ps)[PAD] = (short (*)[PAD])Qs[wave * 16];

    float lsum[4] = {0.f, 0.f, 0.f, 0.f};
    f32x4 o[4];
    #pragma unroll
    for (int dt = 0; dt < 4; dt++) o[dt] = (f32x4){0.f, 0.f, 0.f, 0.f};

    for (int kt = 0; kt < 16; kt++) {
        int cur = kt & 1;
        // issue next-tile loads now; compute below covers their latency
        int4 kreg[2], vreg[2];
        if (kt < 15) {
            int a0 = kc * 1024 + (kt + 1) * 64;
            #pragma unroll
            for (int i = 0; i < 2; i++) {
                int id = i * 256 + tid, r = id >> 3, ch = id & 7;
                kreg[i] = *(const int4*)&Kb[qkbase + (size_t)(a0 + r) * 256 + ch * 8];
                vreg[i] = *(const int4*)&Vt[vtbase + (size_t)r * SS + a0 + ch * 8];
            }
        }
        // S = Q K^T (log2 domain)
        f32x4 sv[4];
        #pragma unroll
        for (int nt = 0; nt < 4; nt++) sv[nt] = (f32x4){0.f, 0.f, 0.f, 0.f};
        #pragma unroll
        for (int nt = 0; nt < 4; nt++) {
            bf16x8 bk0 = *(const bf16x8*)&Ks[cur][nt * 16 + c16][quad * 8];
            bf16x8 bk1 = *(const bf16x8*)&Ks[cur][nt * 16 + c16][32 + quad * 8];
            sv[nt] = __builtin_amdgcn_mfma_f32_16x16x32_bf16(aq0, bk0, sv[nt], 0, 0, 0);
            sv[nt] = __builtin_amdgcn_mfma_f32_16x16x32_bf16(aq1, bk1, sv[nt], 0, 0, 0);
        }
        #pragma unroll
        for (int nt = 0; nt < 4; nt++)
            #pragma unroll
            for (int r = 0; r < 4; r++) sv[nt][r] = __builtin_exp2f(sv[nt][r]);
        #pragma unroll
        for (int r = 0; r < 4; r++)
            lsum[r] += (sv[0][r] + sv[1][r]) + (sv[2][r] + sv[3][r]);
        // P -> per-wave LDS tile (C-layout), re-read as A-fragments
        #pragma unroll
        for (int nt = 0; nt < 4; nt++)
            #pragma unroll
            for (int r = 0; r < 4; r++)
                Ps[quad * 4 + r][nt * 16 + c16] = f2bf_r(sv[nt][r]);
        #pragma unroll
        for (int ks = 0; ks < 64; ks += 32) {
            bf16x8 ap = *(const bf16x8*)&Ps[c16][ks + quad * 8];
            #pragma unroll
            for (int dt = 0; dt < 4; dt++) {
                bf16x8 bv = *(const bf16x8*)&Vs[cur][dt * 16 + c16][ks + quad * 8];
                o[dt] = __builtin_amdgcn_mfma_f32_16x16x32_bf16(ap, bv, o[dt], 0, 0, 0);
            }
        }
        // write prefetched tile into the other buffer (regs die here, pre-barrier)
        if (kt < 15) {
            #pragma unroll
            for (int i = 0; i < 2; i++) {
                int id = i * 256 + tid, r = id >> 3, ch = id & 7;
                *(int4*)&Ks[cur ^ 1][r][ch * 8] = kreg[i];
                *(int4*)&Vs[cur ^ 1][r][ch * 8] = vreg[i];
            }
        }
        __syncthreads();
    }
    #pragma unroll
    for (int off = 1; off < 16; off <<= 1)
        #pragma unroll
        for (int r = 0; r < 4; r++) lsum[r] += __shfl_xor(lsum[r], off);
    #pragma unroll
    for (int dt = 0; dt < 4; dt++)
        #pragma unroll
        for (int r = 0; r < 4; r++) {
            int row = q0 + wave * 16 + quad * 4 + r;
            Opart[(pbase + row) * 64 + dt * 16 + c16] = o[dt][r];
        }
    if (c16 == 0)
        #pragma unroll
        for (int r = 0; r < 4; r++)
            Lpart[pbase + q0 + wave * 16 + quad * 4 + r] = lsum[r];
}

// ---------- output projection, BM=64 BN=128, fused K-split combine ----------
__global__ __launch_bounds__(256) void outproj_kernel(const float* __restrict__ Op,
                                                      const float* __restrict__ Lp,
                                                      const short* __restrict__ Wo4,
                                                      float* __restrict__ out) {
    __shared__ alignas(16) short As[64][72];
    __shared__ alignas(16) short Bs[128][72];
    int tid = threadIdx.x;
    int wave = tid >> 6, lane = tid & 63, quad = lane >> 4, c16 = lane & 15;
    int wm = wave >> 1, wn = wave & 1;
    int m0 = blockIdx.x * 64, n0 = blockIdx.y * 128;

    f32x4 acc[2][4];
    #pragma unroll
    for (int i = 0; i < 2; i++)
        #pragma unroll
        for (int j = 0; j < 4; j++) acc[i][j] = (f32x4){0.f, 0.f, 0.f, 0.f};

    for (int k0 = 0; k0 < 256; k0 += 64) {
        int h = k0 >> 6;
        #pragma unroll
        for (int i = 0; i < 4; i++) {
            int id = i * 256 + tid, r = id >> 4, ch = id & 15;
            int row = m0 + r, b = row >> 11, s = row & (SS - 1);
            int bh = b * 4 + h;
            size_t pidx = ((size_t)bh * SS + s) * 64 + ch * 4;
            float4 a = *(const float4*)&Op[pidx];
            float4 c = *(const float4*)&Op[pidx + (size_t)16 * SS * 64];
            float l = Lp[(size_t)bh * SS + s] + Lp[(size_t)(16 + bh) * SS + s];
            float rl = __builtin_amdgcn_rcpf(l);
            uint2 u;
            u.x = pk_bf16((a.x + c.x) * rl, (a.y + c.y) * rl);
            u.y = pk_bf16((a.z + c.z) * rl, (a.w + c.w) * rl);
            *(uint2*)&As[r][ch * 4] = u;
        }
        #pragma unroll
        for (int i = 0; i < 4; i++) {
            int id = i * 256 + tid, r = id >> 3, ch = id & 7;
            *(int4*)&Bs[r][ch * 8] =
                *(const int4*)&Wo4[(size_t)(n0 + r) * 256 + k0 + ch * 8];
        }
        __syncthreads();
        #pragma unroll
        for (int ks = 0; ks < 64; ks += 32) {
            bf16x8 af[2], bfr[4];
            #pragma unroll
            for (int mt = 0; mt < 2; mt++)
                af[mt] = *(const bf16x8*)&As[wm * 32 + mt * 16 + c16][ks + quad * 8];
            #pragma unroll
            for (int nt = 0; nt < 4; nt++)
                bfr[nt] = *(const bf16x8*)&Bs[wn * 64 + nt * 16 + c16][ks + quad * 8];
            #pragma unroll
            for (int mt = 0; mt < 2; mt++)
                #pragma unroll
                for (int nt = 0; nt < 4; nt++)
                    acc[mt][nt] = __builtin_amdgcn_mfma_f32_16x16x32_bf16(
                        af[mt], bfr[nt], acc[mt][nt], 0, 0, 0);
        }
        __syncthreads();
    }
    #pragma unroll
    for (int mt = 0; mt < 2; mt++)
        #pragma unroll
        for (int nt = 0; nt < 4; nt++) {
            int col = n0 + wn * 64 + nt * 16 + c16;
            int rowb = m0 + wm * 32 + mt * 16 + quad * 4;
            #pragma unroll
            for (int r = 0; r < 4; r++)
                out[(size_t)(rowb + r) * 1024 + col] = acc[mt][nt][r];
        }
}

extern "C" void kernel_launch(void* const* d_in, const int* in_sizes, int n_in,
                              void* d_out, int out_size, void* d_ws, size_t ws_size,
                              hipStream_t stream) {
    const float* q  = (const float*)d_in[0];
    const float* kv = (const float*)d_in[1];
    const float* Wq = (const float*)d_in[2];
    const float* Wk = (const float*)d_in[3];
    const float* Wv = (const float*)d_in[4];
    const float* Wo = (const float*)d_in[5];
    float* out = (float*)d_out;

    short* Qb    = (short*)d_ws;           // 2097152 bf16
    short* Kb    = Qb + 2097152;           // 2097152
    short* Vt    = Kb + 2097152;           // 2097152 (pre-transposed [b*256+h*64+d][s])
    short* Wall  = Vt + 2097152;           // 786432
    short* Wo4   = Wall + 786432;          // 262144
    float2* RT   = (float2*)(Wo4 + 262144);    // 65536 float2
    float* Opart = (float*)(RT + 65536);   // 4194304 fp32
    float* Lpart = Opart + 4194304;        // 65536 fp32

    prep_kernel<<<240, 256, 0, stream>>>(Wq, Wk, Wv, Wo, Wall, Wo4, RT);

    proj_kernel<<<dim3(128, 12), 256, 0, stream>>>(q, kv, Wall, RT, Qb, Kb, Vt);

    attn_kernel<<<dim3(32, 16, 2), 256, 0, stream>>>(Qb, Kb, Vt, Opart, Lpart);

    outproj_kernel<<<dim3(128, 8), 256, 0, stream>>>(Opart, Lpart, Wo4, out);
}